// Round 6
// baseline (1981.071 us; speedup 1.0000x reference)
//
#include <hip/hip_runtime.h>
#include <hip/hip_bf16.h>

typedef unsigned short u16;
typedef unsigned int u32;
typedef __attribute__((ext_vector_type(8))) short short8;
typedef __attribute__((ext_vector_type(4))) float f32x4;

#define DEVI static __device__ __forceinline__

DEVI u16 f2b(float f) {
    union { float f; unsigned v; } x; x.f = f;
    unsigned r = x.v + 0x7fffu + ((x.v >> 16) & 1u);
    return (u16)(r >> 16);
}
DEVI float b2f(u16 u) { union { unsigned v; float f; } x; x.v = ((unsigned)u) << 16; return x.f; }

#define MFMA(a, b, c) __builtin_amdgcn_mfma_f32_16x16x32_bf16((a), (b), (c), 0, 0, 0)

// XOR-swizzle for [64][128] bf16 A-tiles: permute 16B granules within a row
// by row&7 so column-strided b128 reads spread over all 32 banks.
DEVI int swz(int row, int col) {
    return row * 128 + ((((col >> 3) ^ (row & 7))) << 3) + (col & 7);
}

// ws layout:
//   [0 .. RW_END) bf16 elems           : repacked MFMA B-fragment weights
//   then f32 region (FT_* float offs)  : transposed f32 weights for VALU phases
//   then qpre f32 [2][4][128]
#define RW_PEW     0
#define RW_I1M0_WK 16384
#define RW_I1M0_WV 49152
#define RW_I1M1_WQ 81920
#define RW_I1M1_WO 114688
#define RW_I2M0_WK 131072
#define RW_I2M0_WV 147456
#define RW_I2M1_WQ 163840
#define RW_I2M1_WO 180224
#define RW_DEC_WK  196608
#define RW_DEC_WV  212992
#define RW_END     229376   // bf16 elems

// f32 transposed weights, offsets in floats from ft base
#define FT_I1M0_WO 0
#define FT_I2M0_WO 16384
#define FT_I1M1_WK 32768
#define FT_I1M1_WV 49152
#define FT_I2M1_WK 65536
#define FT_I2M1_WV 81920
#define FT_DEC_WO  98304
#define FT_DEC_WQ  114688
#define FT_OUT_W   147456
#define FT_END     180224

#define PA 128   // logical pitch of [64][128] tiles (swizzled addressing via swz())
#define PT 66    // pitch of transposed-K buffers [128][66]: col stride 66*2B ≡ 33 dwords
                 // -> bank advances by 1 per col, breaking the 16-way write conflict at PT=64
#define SCALE 0.08838834764831845f  // 1/sqrt(128)

struct Params {
    const float* in[49];   // ALL reference inputs are float32
    const u16* wrep;       // repacked bf16 weight fragments
    const float* ft;       // transposed f32 weights
    const float* qpre;     // [2][4][128] fp32 (precomputed I@wq+bq for i1m0 / i2m0)
    float* out;            // float32 output
};

struct RepArgs {
    const float* src[11];
    const float* tsrc[9];
    u16* dst;
    float* fdst;
    float* qpre;
    const float* I1; const float* wq1; const float* bq1;
    const float* I2; const float* wq2; const float* bq2;
};

// Repack f32 weights [K][N] row-major -> bf16 MFMA B fragments (t < 28672),
// transposed f32 copies wT[n*K+k] = w[k*N+n] (28672 <= t < 51200),
// batch-independent Qp for the two ISAB m0 blocks (t >= 51200).
__global__ void repack_kernel(RepArgs a) {
    const int offs[11] = {RW_PEW, RW_I1M0_WK, RW_I1M0_WV, RW_I1M1_WQ, RW_I1M1_WO,
                          RW_I2M0_WK, RW_I2M0_WV, RW_I2M1_WQ, RW_I2M1_WO, RW_DEC_WK, RW_DEC_WV};
    const int Ks[11] = {64, 256, 256, 256, 128, 128, 128, 128, 128, 128, 128};
    const int Ns[11] = {256, 128, 128, 128, 128, 128, 128, 128, 128, 128, 128};
    int t = blockIdx.x * 256 + threadIdx.x;
    if (t < 28672) {
        int m = 0, u = t;
        for (m = 0; m < 11; ++m) {
            int un = (Ks[m] * Ns[m]) >> 3;
            if (u < un) break;
            u -= un;
        }
        int l = u & 63, f = u >> 6;
        int ksteps = Ks[m] >> 5;
        int nt = f / ksteps, ks = f - nt * ksteps;
        int N = Ns[m];
        const float* s = a.src[m] + (ks * 32 + (l >> 4) * 8) * N + nt * 16 + (l & 15);
        u16* d = a.dst + offs[m] + ((f * 64 + l) << 3);
        short8 v;
        #pragma unroll
        for (int j = 0; j < 8; ++j) v[j] = (short)f2b(s[j * N]);
        *(short8*)d = v;
    } else if (t < 51200) {
        // transposed f32 repack: each thread writes 8 contiguous k at one n
        const int TK[9] = {128, 128, 128, 128, 128, 128, 128, 256, 128};
        const int TN[9] = {128, 128, 128, 128, 128, 128, 128, 128, 256};
        const int TOFF[9] = {FT_I1M0_WO, FT_I2M0_WO, FT_I1M1_WK, FT_I1M1_WV,
                             FT_I2M1_WK, FT_I2M1_WV, FT_DEC_WO, FT_DEC_WQ, FT_OUT_W};
        int u = t - 28672;
        int m = 0;
        for (m = 0; m < 9; ++m) {
            int un = (TK[m] * TN[m]) >> 3;
            if (u < un) break;
            u -= un;
        }
        int K = TK[m], N = TN[m];
        int kc = K >> 3;
        int n = u / kc, k0 = (u - n * kc) << 3;
        const float* s = a.tsrc[m] + k0 * N + n;
        float* d = a.fdst + TOFF[m] + n * K + k0;
        f32x4 v0, v1;
        #pragma unroll
        for (int j = 0; j < 4; ++j) v0[j] = s[j * N];
        #pragma unroll
        for (int j = 0; j < 4; ++j) v1[j] = s[(4 + j) * N];
        *(f32x4*)d = v0;
        *(f32x4*)(d + 4) = v1;
    } else {
        int q_t = t - 51200;             // 0..1023
        int which = q_t >> 9, q = (q_t >> 7) & 3, n = q_t & 127;
        const float* I  = which ? a.I2  : a.I1;
        const float* wq = which ? a.wq2 : a.wq1;
        const float* bq = which ? a.bq2 : a.bq1;
        float acc = bq[n];
        for (int k = 0; k < 128; ++k) acc += I[q * 128 + k] * wq[k * 128 + n];
        a.qpre[q_t] = acc;
    }
}

// [64,128] = A(lds, swizzled [64][128] bf16) @ Brep(K=128, repacked bf16) + bias(f32)
// MODE 0: out swizzled [64][128]   MODE 1: transposed out[col*PT+row] (unswizzled)
// MODE 2: out = A + relu(D+bias)  (residual = A), out swizzled
template <int MODE>
DEVI void gemm128(const u16* A, const u16* __restrict__ Brep,
                  const float* __restrict__ bias, u16* out, int tid) {
    int l = tid & 63, w = tid >> 6;
    int lr = l & 15, lq = l >> 4;
    int Mt = w & 3, Ntb = (w >> 2) * 4;
    f32x4 z = {0.f, 0.f, 0.f, 0.f};
    f32x4 acc[4];
    #pragma unroll
    for (int i = 0; i < 4; ++i) acc[i] = z;
    int arow = Mt * 16 + lr;
    #pragma unroll
    for (int ks = 0; ks < 4; ++ks) {
        short8 af = *(const short8*)(A + swz(arow, ks * 32 + lq * 8));
        #pragma unroll
        for (int i = 0; i < 4; ++i) {
            int nt = Ntb + i;
            short8 bfr = *(const short8*)(Brep + (((nt << 2) + ks) * 64 + l) * 8);
            acc[i] = MFMA(af, bfr, acc[i]);
        }
    }
    #pragma unroll
    for (int i = 0; i < 4; ++i) {
        int col = (Ntb + i) * 16 + lr;
        float bv = bias[col];
        #pragma unroll
        for (int r = 0; r < 4; ++r) {
            int row = Mt * 16 + lq * 4 + r;
            float v = acc[i][r] + bv;
            if (MODE == 2) v = b2f(A[swz(row, col)]) + fmaxf(v, 0.f);
            if (MODE == 1) out[col * PT + row] = f2b(v);
            else           out[swz(row, col)] = f2b(v);
        }
    }
}

// ISAB m0 attention: Sq=4 (qpre fp32), Sk=64. KT=[128][PT] bf16 (unswizzled),
// V = swizzled [64][128] bf16.
// Wave w owns complete score rows w and w+8 (row = h*4+q), lane = k:
// scores+softmax fused in-wave via 64-lane shfl reduction (no barrier).
// scr aliases KT's storage as float (KT dead after the score phase):
//   scr[0..512)   = O^T  [n][q]
//   scr[512..1024)= H'^T [n][q]   (survives until att_m1's K2/V2 phase)
DEVI void att_m0(const float* __restrict__ qpre, const float* __restrict__ woT,
                 const float* __restrict__ bo, const u16* KT, const u16* V,
                 float* scr, float* sS, int tid) {
    #pragma unroll
    for (int ii = 0; ii < 2; ++ii) {         // fused scores + softmax, row/wave
        int row = (tid >> 6) + ii * 8;       // = h*4+q
        int h = row >> 2, q = row & 3, k = tid & 63;
        const float* qp = qpre + q * 128 + h * 32;
        const u16* kp = KT + (h * 32) * PT + k;
        float s = 0.f;
        #pragma unroll
        for (int d8 = 0; d8 < 8; ++d8) {
            f32x4 q4 = *(const f32x4*)(qp + d8 * 4);
            #pragma unroll
            for (int j = 0; j < 4; ++j) s += q4[j] * b2f(kp[(d8 * 4 + j) * PT]);
        }
        s *= SCALE;
        float m = s;
        #pragma unroll
        for (int off = 1; off < 64; off <<= 1) m = fmaxf(m, __shfl_xor(m, off));
        float e = __expf(s - m);
        float su = e;
        #pragma unroll
        for (int off = 1; off < 64; off <<= 1) su += __shfl_xor(su, off);
        sS[row * 64 + k] = e / su;
    }
    __syncthreads();
    {   // O^T = qpre + A*V  -> scr[n*4+q]  (KT dead now; conflict-free writes)
        int q = tid & 3, n = tid >> 2, h = n >> 5;
        float o = qpre[q * 128 + n];
        const float* ar = sS + (h * 4 + q) * 64;
        #pragma unroll 8
        for (int k8 = 0; k8 < 16; ++k8) {
            f32x4 a4 = *(const f32x4*)(ar + k8 * 4);
            #pragma unroll
            for (int j = 0; j < 4; ++j) o += a4[j] * b2f(V[swz(k8 * 4 + j, n)]);
        }
        scr[n * 4 + q] = o;
    }
    __syncthreads();
    if (tid < 256) {   // O@wo partials (k split 2), transposed f32 weights
        int n = tid & 127, c = tid >> 7;
        const float* wp = woT + n * 128 + c * 64;
        f32x4 acc = {0.f, 0.f, 0.f, 0.f};
        #pragma unroll 4
        for (int k4 = 0; k4 < 16; ++k4) {
            f32x4 w4 = *(const f32x4*)(wp + k4 * 4);
            #pragma unroll
            for (int j = 0; j < 4; ++j) {
                f32x4 o4 = *(const f32x4*)(scr + (c * 64 + k4 * 4 + j) * 4);
                acc[0] += o4[0] * w4[j]; acc[1] += o4[1] * w4[j];
                acc[2] += o4[2] * w4[j]; acc[3] += o4[3] * w4[j];
            }
        }
        *(f32x4*)(sS + c * 512 + n * 4) = acc;
    }
    __syncthreads();
    {   // H'^T = O + relu(O@wo + bo) -> scr[512 + n*4 + q]
        int q = tid & 3, n = tid >> 2;
        float val = sS[n * 4 + q] + sS[512 + n * 4 + q] + bo[n];
        scr[512 + n * 4 + q] = scr[n * 4 + q] + fmaxf(val, 0.f);
    }
    __syncthreads();
}

// ISAB m1 attention: Sq=64 (QpO = swizzled Qp tile, bf16), Sk=4.
// HT = H'^T [128][4] f32 (R0f+512). kv = raw f32 scratch (overlay on a dead tile):
// K2 = kv[0..512), V2 = kv[512..1024).
// O = Qp + A*V2 is written IN PLACE over QpO (each element read once by its
// owner lane strictly before the write -> no hazard).
DEVI void att_m1(u16* QpO, const float* __restrict__ wkT, const float* __restrict__ bk,
                 const float* __restrict__ wvT, const float* __restrict__ bv,
                 float* kv, const float* HT, float* sS, int tid) {
    if (tid < 256) {   // K2 = H@wk+bk (tid<128), V2 = H@wv+bv (tid>=128)
        int n = tid & 127, half = tid >> 7;
        const float* wp = (half ? wvT : wkT) + n * 128;
        const float* bsel = half ? bv : bk;
        f32x4 acc = {0.f, 0.f, 0.f, 0.f};
        #pragma unroll 4
        for (int j4 = 0; j4 < 32; ++j4) {
            f32x4 w4 = *(const f32x4*)(wp + j4 * 4);
            #pragma unroll
            for (int j = 0; j < 4; ++j) {
                f32x4 h4 = *(const f32x4*)(HT + (j4 * 4 + j) * 4);
                acc[0] += h4[0] * w4[j]; acc[1] += h4[1] * w4[j];
                acc[2] += h4[2] * w4[j]; acc[3] += h4[3] * w4[j];
            }
        }
        float bb = bsel[n];
        float* dst = kv + half * 512;
        dst[0 * 128 + n] = acc[0] + bb; dst[1 * 128 + n] = acc[1] + bb;
        dst[2 * 128 + n] = acc[2] + bb; dst[3 * 128 + n] = acc[3] + bb;
    }
    __syncthreads();
    if (tid < 256) {   // scores + softmax over k=4, per (h,q) in-thread
        int h = tid >> 6, q = tid & 63;
        const float* kb = kv + h * 32;   // K2
        f32x4 s = {0.f, 0.f, 0.f, 0.f};
        #pragma unroll
        for (int d8 = 0; d8 < 4; ++d8) {
            short8 q8 = *(const short8*)(QpO + swz(q, h * 32 + d8 * 8));
            f32x4 kra[4], krb[4];
            #pragma unroll
            for (int c = 0; c < 4; ++c) {
                kra[c] = *(const f32x4*)(kb + c * 128 + d8 * 8);
                krb[c] = *(const f32x4*)(kb + c * 128 + d8 * 8 + 4);
            }
            #pragma unroll
            for (int j = 0; j < 4; ++j) {
                float qv = b2f((u16)q8[j]);
                s[0] += qv * kra[0][j]; s[1] += qv * kra[1][j];
                s[2] += qv * kra[2][j]; s[3] += qv * kra[3][j];
            }
            #pragma unroll
            for (int j = 0; j < 4; ++j) {
                float qv = b2f((u16)q8[4 + j]);
                s[0] += qv * krb[0][j]; s[1] += qv * krb[1][j];
                s[2] += qv * krb[2][j]; s[3] += qv * krb[3][j];
            }
        }
        float s0 = s[0] * SCALE, s1 = s[1] * SCALE, s2 = s[2] * SCALE, s3 = s[3] * SCALE;
        float m = fmaxf(fmaxf(s0, s1), fmaxf(s2, s3));
        s0 = __expf(s0 - m); s1 = __expf(s1 - m); s2 = __expf(s2 - m); s3 = __expf(s3 - m);
        float inv = 1.f / (s0 + s1 + s2 + s3);
        f32x4 a; a[0] = s0 * inv; a[1] = s1 * inv; a[2] = s2 * inv; a[3] = s3 * inv;
        *(f32x4*)(sS + (h * 64 + q) * 4) = a;
    }
    __syncthreads();
    #pragma unroll
    for (int ii = 0; ii < 16; ++ii) {   // O = Qp + A*V2, in place
        int idx = tid + ii * 512;
        int q = idx >> 7, n = idx & 127, h = n >> 5;
        f32x4 a4 = *(const f32x4*)(sS + (h * 64 + q) * 4);
        int e = swz(q, n);
        float o = b2f(QpO[e]);
        o += a4[0] * kv[512 + 0 * 128 + n] + a4[1] * kv[512 + 1 * 128 + n]
           + a4[2] * kv[512 + 2 * 128 + n] + a4[3] * kv[512 + 3 * 128 + n];
        QpO[e] = f2b(o);
    }
    __syncthreads();
}

__global__ __launch_bounds__(512, 3) void fused_kernel(Params P) {
    __shared__ __align__(16) u16 R0[128 * PT];   // 16.5 KB (K^T tile / f32 scr overlay)
    __shared__ __align__(16) u16 R1[64 * 128];   // 16 KB  (swizzled A-tile / f32 overlay)
    __shared__ __align__(16) u16 R2[64 * 128];   // 16 KB  (swizzled A-tile)
    __shared__ __align__(16) float sS[1024];     // 4 KB   -> 52.5 KB total, 3 blocks/CU
    float* R0f = (float*)R0;
    float* R1f = (float*)R1;

    const int b = blockIdx.x;
    const int tid = threadIdx.x;
    const int l = tid & 63, w = tid >> 6;
    const int lr = l & 15, lq = l >> 4;
    const int Mt = w & 3, Ntb = (w >> 2) * 4;

    const float* v_in = P.in[0] + b * (64 * 256);
    const float* W_in = P.in[1] + b * (64 * 64);
    const float* Q_in = P.in[2] + b * 256;
    const float* ft = P.ft;

    f32x4 z = {0.f, 0.f, 0.f, 0.f};

    // ---- Phase 1: RankAdd (Vh = v + W@pe_w + pe_b) staged into R1 (cols 0..127)
    //      and R2 (cols 128..255), then three K=256 GEMMs as sequential passes. ----
    {
        const float* wrow = W_in + (Mt * 16 + lr) * 64 + lq * 8;
        #pragma unroll 1
        for (int p = 0; p < 2; ++p) {
            f32x4 ar[4];
            #pragma unroll
            for (int i = 0; i < 4; ++i) ar[i] = z;
            #pragma unroll
            for (int ks = 0; ks < 2; ++ks) {   // W @ pe_w, K=64 (f32 -> bf16 A-frag)
                f32x4 w0 = *(const f32x4*)(wrow + ks * 32);
                f32x4 w1 = *(const f32x4*)(wrow + ks * 32 + 4);
                short8 af;
                #pragma unroll
                for (int j = 0; j < 4; ++j) { af[j] = (short)f2b(w0[j]); af[4 + j] = (short)f2b(w1[j]); }
                #pragma unroll
                for (int i = 0; i < 4; ++i) {
                    int ntg = p * 8 + Ntb + i;
                    short8 bfr = *(const short8*)(P.wrep + RW_PEW + ((ntg * 2 + ks) * 64 + l) * 8);
                    ar[i] = MFMA(af, bfr, ar[i]);
                }
            }
            u16* dst = p ? R2 : R1;
            #pragma unroll
            for (int i = 0; i < 4; ++i) {
                int coll = (Ntb + i) * 16 + lr;
                int colg = p * 128 + coll;
                float pb = P.in[4][colg];   // pe_b
                #pragma unroll
                for (int r = 0; r < 4; ++r) {
                    int row = Mt * 16 + lq * 4 + r;
                    dst[swz(row, coll)] = f2b(ar[i][r] + pb + v_in[row * 256 + colg]);
                }
            }
        }
        __syncthreads();

        // K-pass: Kp = Vh @ wk  -> Kp^T in R0 (unswizzled [128][PT])
        {
            f32x4 aK[4];
            #pragma unroll
            for (int i = 0; i < 4; ++i) aK[i] = z;
            #pragma unroll
            for (int p = 0; p < 2; ++p) {
                const u16* At = p ? R2 : R1;
                #pragma unroll
                for (int ks = 0; ks < 4; ++ks) {
                    short8 af = *(const short8*)(At + swz(Mt * 16 + lr, ks * 32 + lq * 8));
                    int kk = p * 4 + ks;
                    #pragma unroll
                    for (int i = 0; i < 4; ++i) {
                        int nt = Ntb + i;
                        short8 b0 = *(const short8*)(P.wrep + RW_I1M0_WK + ((nt * 8 + kk) * 64 + l) * 8);
                        aK[i] = MFMA(af, b0, aK[i]);
                    }
                }
            }
            #pragma unroll
            for (int i = 0; i < 4; ++i) {
                int col = (Ntb + i) * 16 + lr;
                float bkv = P.in[9][col];    // i1_m0_bk
                #pragma unroll
                for (int r = 0; r < 4; ++r) {
                    int row = Mt * 16 + lq * 4 + r;
                    R0[col * PT + row] = f2b(aK[i][r] + bkv);
                }
            }
        }
        // Q+V pass: Vp = Vh @ wv, Qp1 = Vh @ i1_m1_wq (held in regs until Vh dead)
        {
            f32x4 aV[4], aQ[4];
            #pragma unroll
            for (int i = 0; i < 4; ++i) { aV[i] = z; aQ[i] = z; }
            #pragma unroll
            for (int p = 0; p < 2; ++p) {
                const u16* At = p ? R2 : R1;
                #pragma unroll
                for (int ks = 0; ks < 4; ++ks) {
                    short8 af = *(const short8*)(At + swz(Mt * 16 + lr, ks * 32 + lq * 8));
                    int kk = p * 4 + ks;
                    #pragma unroll
                    for (int i = 0; i < 4; ++i) {
                        int nt = Ntb + i;
                        short8 b1 = *(const short8*)(P.wrep + RW_I1M0_WV + ((nt * 8 + kk) * 64 + l) * 8);
                        aV[i] = MFMA(af, b1, aV[i]);
                        short8 b2v = *(const short8*)(P.wrep + RW_I1M1_WQ + ((nt * 8 + kk) * 64 + l) * 8);
                        aQ[i] = MFMA(af, b2v, aQ[i]);
                    }
                }
            }
            __syncthreads();   // all Vh reads done; R1/R2 can be overwritten
            #pragma unroll
            for (int i = 0; i < 4; ++i) {
                int col = (Ntb + i) * 16 + lr;
                float bvv = P.in[11][col];   // i1_m0_bv
                float bqv = P.in[15][col];   // i1_m1_bq
                #pragma unroll
                for (int r = 0; r < 4; ++r) {
                    int row = Mt * 16 + lq * 4 + r;
                    R1[swz(row, col)] = f2b(aV[i][r] + bvv);
                    R2[swz(row, col)] = f2b(aQ[i][r] + bqv);
                }
            }
        }
        __syncthreads();
    }

    // ---- ISAB1 ----
    att_m0(P.qpre, ft + FT_I1M0_WO, P.in[13], R0, R1, R0f, sS, tid);       // H1'^T -> R0f+512
    att_m1(R2, ft + FT_I1M1_WK, P.in[17], ft + FT_I1M1_WV, P.in[19],
           R1f, R0f + 512, sS, tid);                                       // O2 in place (R2)
    gemm128<2>(R2, P.wrep + RW_I1M1_WO, P.in[21], R1, tid);                // X -> R1
    __syncthreads();
    // ---- ISAB2 ----
    gemm128<1>(R1, P.wrep + RW_I2M0_WK, P.in[26], R0, tid);                // Kp3^T -> R0
    gemm128<0>(R1, P.wrep + RW_I2M0_WV, P.in[28], R2, tid);                // Vp3 -> R2
    __syncthreads();
    att_m0(P.qpre + 512, ft + FT_I2M0_WO, P.in[30], R0, R2, R0f, sS, tid); // H2'^T -> R0f+512
    gemm128<0>(R1, P.wrep + RW_I2M1_WQ, P.in[32], R2, tid);                // Qp3 -> R2
    __syncthreads();
    att_m1(R2, ft + FT_I2M1_WK, P.in[34], ft + FT_I2M1_WV, P.in[36],
           R1f, R0f + 512, sS, tid);                                       // O4 in place (R2)
    gemm128<2>(R2, P.wrep + RW_I2M1_WO, P.in[38], R1, tid);                // Xf -> R1
    __syncthreads();
    // ---- decoder MAB ----
    gemm128<1>(R1, P.wrep + RW_DEC_WK, P.in[42], R0, tid);                 // Kpd^T -> R0
    gemm128<0>(R1, P.wrep + RW_DEC_WV, P.in[44], R2, tid);                 // Vpd -> R2
    __syncthreads();
    // R1 (Xf) is dead from here: R1f is the decoder f32 scratch.
    // R1f[0..128) = Qd, R1f[128..256) = O5, R1f[256..384) = o

    {   // Qp_dec partials: [1,256]@[256,128], k split in 4, transposed f32 weights
        int n = tid & 127, c = tid >> 7;
        const float* wp = ft + FT_DEC_WQ + n * 256 + c * 64;
        const float* qq = Q_in + c * 64;
        float acc = 0.f;
        #pragma unroll 8
        for (int k4 = 0; k4 < 16; ++k4) {
            f32x4 w4 = *(const f32x4*)(wp + k4 * 4);
            f32x4 q4 = *(const f32x4*)(qq + k4 * 4);
            acc += q4[0] * w4[0] + q4[1] * w4[1] + q4[2] * w4[2] + q4[3] * w4[3];
        }
        sS[c * 128 + n] = acc;
    }
    __syncthreads();
    if (tid < 128) {   // Qd -> R1f[0..128)
        R1f[tid] = sS[tid] + sS[128 + tid] + sS[256 + tid] + sS[384 + tid] + P.in[40][tid];
    }
    __syncthreads();
    if (w < 4) {   // fused scores + softmax: wave h owns row h, lane = k
        int h = w, k = l;
        const float* qd = R1f + h * 32;
        const u16* kp = R0 + (h * 32) * PT + k;
        float s = 0.f;
        #pragma unroll
        for (int d8 = 0; d8 < 8; ++d8) {
            f32x4 q4 = *(const f32x4*)(qd + d8 * 4);
            #pragma unroll
            for (int j = 0; j < 4; ++j) s += q4[j] * b2f(kp[(d8 * 4 + j) * PT]);
        }
        s *= SCALE;
        float m = s;
        #pragma unroll
        for (int off = 1; off < 64; off <<= 1) m = fmaxf(m, __shfl_xor(m, off));
        float e = __expf(s - m);
        float su = e;
        #pragma unroll
        for (int off = 1; off < 64; off <<= 1) su += __shfl_xor(su, off);
        sS[h * 64 + k] = e / su;
    }
    __syncthreads();
    if (tid < 128) {   // O5 = Qd + A*Vpd -> R1f[128..256)
        int n = tid, h = n >> 5;
        float o = R1f[n];
        const float* arr = sS + h * 64;
        #pragma unroll 8
        for (int k8 = 0; k8 < 16; ++k8) {
            f32x4 a4 = *(const f32x4*)(arr + k8 * 4);
            #pragma unroll
            for (int j = 0; j < 4; ++j) o += a4[j] * b2f(R2[swz(k8 * 4 + j, n)]);
        }
        R1f[128 + n] = o;
    }
    __syncthreads();
    if (tid < 256) {   // O5@dec_wo partials (k split 2) -> sS[256..512)
        int n = tid & 127, c = tid >> 7;
        const float* wp = ft + FT_DEC_WO + n * 128 + c * 64;
        const float* ov = R1f + 128 + c * 64;
        float acc = 0.f;
        #pragma unroll 8
        for (int k4 = 0; k4 < 16; ++k4) {
            f32x4 w4 = *(const f32x4*)(wp + k4 * 4);
            f32x4 o4 = *(const f32x4*)(ov + k4 * 4);
            acc += o4[0] * w4[0] + o4[1] * w4[1] + o4[2] * w4[2] + o4[3] * w4[3];
        }
        sS[256 + c * 128 + n] = acc;
    }
    __syncthreads();
    if (tid < 128) {   // o = O5 + relu(... + bo) -> R1f[256..384)
        float val = sS[256 + tid] + sS[384 + tid] + P.in[46][tid];
        R1f[256 + tid] = R1f[128 + tid] + fmaxf(val, 0.f);
    }
    __syncthreads();
    {   // out = o @ out_w + out_b, k split 2, transposed f32 weights
        int j = tid & 255, c = tid >> 8;
        const float* wp = ft + FT_OUT_W + j * 128 + c * 64;
        const float* ov = R1f + 256 + c * 64;
        float acc = 0.f;
        #pragma unroll 8
        for (int k4 = 0; k4 < 16; ++k4) {
            f32x4 w4 = *(const f32x4*)(wp + k4 * 4);
            f32x4 o4 = *(const f32x4*)(ov + k4 * 4);
            acc += o4[0] * w4[0] + o4[1] * w4[1] + o4[2] * w4[2] + o4[3] * w4[3];
        }
        sS[c * 256 + j] = acc;
    }
    __syncthreads();
    if (tid < 256) {
        P.out[b * 256 + tid] = sS[tid] + sS[256 + tid] + P.in[48][tid];
    }
}

extern "C" void kernel_launch(void* const* d_in, const int* in_sizes, int n_in,
                              void* d_out, int out_size, void* d_ws, size_t ws_size,
                              hipStream_t stream) {
    RepArgs ra;
    const int srcidx[11] = {3, 8, 10, 14, 20, 25, 27, 31, 37, 41, 43};
    for (int i = 0; i < 11; ++i) ra.src[i] = (const float*)d_in[srcidx[i]];
    const int tidx[9] = {12, 29, 16, 18, 33, 35, 45, 39, 47};
    for (int i = 0; i < 9; ++i) ra.tsrc[i] = (const float*)d_in[tidx[i]];
    ra.dst = (u16*)d_ws;
    ra.fdst = (float*)((char*)d_ws + RW_END * 2);
    ra.qpre = ra.fdst + FT_END;
    ra.I1 = (const float*)d_in[5];  ra.wq1 = (const float*)d_in[6];  ra.bq1 = (const float*)d_in[7];
    ra.I2 = (const float*)d_in[22]; ra.wq2 = (const float*)d_in[23]; ra.bq2 = (const float*)d_in[24];
    repack_kernel<<<204, 256, 0, stream>>>(ra);

    Params P;
    for (int i = 0; i < 49; ++i) P.in[i] = (const float*)d_in[i];
    P.wrep = (const u16*)d_ws;
    P.ft = (const float*)((char*)d_ws + RW_END * 2);
    P.qpre = P.ft + FT_END;
    P.out = (float*)d_out;
    fused_kernel<<<4096, 512, 0, stream>>>(P);
}

// Round 7
// 1865.523 us; speedup vs baseline: 1.0619x; 1.0619x over previous
//
#include <hip/hip_runtime.h>
#include <hip/hip_bf16.h>

typedef unsigned short u16;
typedef unsigned int u32;
typedef __attribute__((ext_vector_type(8))) short short8;
typedef __attribute__((ext_vector_type(4))) float f32x4;

#define DEVI static __device__ __forceinline__

DEVI u16 f2b(float f) {
    union { float f; unsigned v; } x; x.f = f;
    unsigned r = x.v + 0x7fffu + ((x.v >> 16) & 1u);
    return (u16)(r >> 16);
}
DEVI float b2f(u16 u) { union { unsigned v; float f; } x; x.v = ((unsigned)u) << 16; return x.f; }

#define MFMA(a, b, c) __builtin_amdgcn_mfma_f32_16x16x32_bf16((a), (b), (c), 0, 0, 0)

// XOR-swizzle for [64][128] bf16 A-tiles (16B granule permuted by row&7).
DEVI int swz(int row, int col) {
    return row * 128 + ((((col >> 3) ^ (row & 7))) << 3) + (col & 7);
}

// ws layout: bf16 MFMA B-fragments, then f32 transposed weights, qpre, qk tables.
#define RW_PEW     0
#define RW_I1M0_WK 16384
#define RW_I1M0_WV 49152
#define RW_I1M1_WQ 81920
#define RW_I1M1_WO 114688
#define RW_I2M0_WK 131072
#define RW_I2M0_WV 147456
#define RW_I2M1_WQ 163840
#define RW_I2M1_WO 180224
#define RW_DEC_WK  196608
#define RW_DEC_WV  212992
#define RW_END     229376   // bf16 elems

#define FT_I1M0_WO 0
#define FT_I2M0_WO 16384
#define FT_I1M1_WK 32768
#define FT_I1M1_WV 49152
#define FT_I2M1_WK 65536
#define FT_I2M1_WV 81920
#define FT_DEC_WO  98304
#define FT_DEC_WQ  114688
#define FT_OUT_W   147456
#define FT_END     180224
// f32 appendix (offsets in floats from ft base)
#define FQ_QPRE    FT_END              // [2][4][128]
#define FQ_QK1     (FT_END + 1024)     // [16][256] + [16] bias-dots
#define FQ_QK2     (FT_END + 1024 + 4112)  // [16][128] + [16]

#define SCALE 0.08838834764831845f  // 1/sqrt(128)

struct Params {
    const float* in[49];
    const u16* wrep;
    const float* ft;
    const float* qpre;   // [2][4][128]
    const float* qk1;    // [16][256]+[16]
    const float* qk2;    // [16][128]+[16]
    float* out;
};

struct RepArgs {
    const float* src[11];
    const float* tsrc[9];
    u16* dst;
    float* fdst;
    float* qpre;
    const float* I1; const float* wq1; const float* bq1;
    const float* I2; const float* wq2; const float* bq2;
};

__global__ void repack_kernel(RepArgs a) {
    const int offs[11] = {RW_PEW, RW_I1M0_WK, RW_I1M0_WV, RW_I1M1_WQ, RW_I1M1_WO,
                          RW_I2M0_WK, RW_I2M0_WV, RW_I2M1_WQ, RW_I2M1_WO, RW_DEC_WK, RW_DEC_WV};
    const int Ks[11] = {64, 256, 256, 256, 128, 128, 128, 128, 128, 128, 128};
    const int Ns[11] = {256, 128, 128, 128, 128, 128, 128, 128, 128, 128, 128};
    int t = blockIdx.x * 256 + threadIdx.x;
    if (t < 28672) {
        int m = 0, u = t;
        for (m = 0; m < 11; ++m) {
            int un = (Ks[m] * Ns[m]) >> 3;
            if (u < un) break;
            u -= un;
        }
        int l = u & 63, f = u >> 6;
        int ksteps = Ks[m] >> 5;
        int nt = f / ksteps, ks = f - nt * ksteps;
        int N = Ns[m];
        const float* s = a.src[m] + (ks * 32 + (l >> 4) * 8) * N + nt * 16 + (l & 15);
        u16* d = a.dst + offs[m] + ((f * 64 + l) << 3);
        short8 v;
        #pragma unroll
        for (int j = 0; j < 8; ++j) v[j] = (short)f2b(s[j * N]);
        *(short8*)d = v;
    } else if (t < 51200) {
        const int TK[9] = {128, 128, 128, 128, 128, 128, 128, 256, 128};
        const int TN[9] = {128, 128, 128, 128, 128, 128, 128, 128, 256};
        const int TOFF[9] = {FT_I1M0_WO, FT_I2M0_WO, FT_I1M1_WK, FT_I1M1_WV,
                             FT_I2M1_WK, FT_I2M1_WV, FT_DEC_WO, FT_DEC_WQ, FT_OUT_W};
        int u = t - 28672;
        int m = 0;
        for (m = 0; m < 9; ++m) {
            int un = (TK[m] * TN[m]) >> 3;
            if (u < un) break;
            u -= un;
        }
        int K = TK[m], N = TN[m];
        int kc = K >> 3;
        int n = u / kc, k0 = (u - n * kc) << 3;
        const float* s = a.tsrc[m] + k0 * N + n;
        float* d = a.fdst + TOFF[m] + n * K + k0;
        f32x4 v0, v1;
        #pragma unroll
        for (int j = 0; j < 4; ++j) v0[j] = s[j * N];
        #pragma unroll
        for (int j = 0; j < 4; ++j) v1[j] = s[(4 + j) * N];
        *(f32x4*)d = v0;
        *(f32x4*)(d + 4) = v1;
    } else {
        int q_t = t - 51200;             // 0..1023
        int which = q_t >> 9, q = (q_t >> 7) & 3, n = q_t & 127;
        const float* I  = which ? a.I2  : a.I1;
        const float* wq = which ? a.wq2 : a.wq1;
        const float* bq = which ? a.bq2 : a.bq1;
        float acc = bq[n];
        for (int k = 0; k < 128; ++k) acc += I[q * 128 + k] * wq[k * 128 + n];
        a.qpre[q_t] = acc;
    }
}

struct QkArgs {
    const float* qpre;
    const float* wk1; const float* bk1;   // [256][128], [128]
    const float* wk2; const float* bk2;   // [128][128], [128]
    float* qk1; float* qk2;
};

// qkh[h,q,j] = sum_{d in head h} qpre[q,d] * wk[j,d]; bias-dots appended.
__global__ void qk_kernel(QkArgs a) {
    int t = blockIdx.x * 256 + threadIdx.x;
    if (t < 4096) {
        int r = t >> 8, j = t & 255;
        int h = r >> 2, q = r & 3;
        const float* qp = a.qpre + q * 128 + h * 32;
        const float* wp = a.wk1 + j * 128 + h * 32;
        float s = 0.f;
        #pragma unroll
        for (int d = 0; d < 32; ++d) s += qp[d] * wp[d];
        a.qk1[r * 256 + j] = s;
    } else if (t < 6144) {
        int u = t - 4096;
        int r = u >> 7, j = u & 127;
        int h = r >> 2, q = r & 3;
        const float* qp = a.qpre + 512 + q * 128 + h * 32;
        const float* wp = a.wk2 + j * 128 + h * 32;
        float s = 0.f;
        #pragma unroll
        for (int d = 0; d < 32; ++d) s += qp[d] * wp[d];
        a.qk2[r * 128 + j] = s;
    } else if (t < 6160) {
        int r = t - 6144; int h = r >> 2, q = r & 3;
        const float* qp = a.qpre + q * 128 + h * 32;
        const float* bp = a.bk1 + h * 32;
        float s = 0.f;
        #pragma unroll
        for (int d = 0; d < 32; ++d) s += qp[d] * bp[d];
        a.qk1[4096 + r] = s;
    } else if (t < 6176) {
        int r = t - 6160; int h = r >> 2, q = r & 3;
        const float* qp = a.qpre + 512 + q * 128 + h * 32;
        const float* bp = a.bk2 + h * 32;
        float s = 0.f;
        #pragma unroll
        for (int d = 0; d < 32; ++d) s += qp[d] * bp[d];
        a.qk2[2048 + r] = s;
    }
}

// [64,128] = A(swizzled) @ Brep(K=128) + bias.  MODE 0: plain out; MODE 2: A + relu(D+bias).
template <int MODE>
DEVI void gemm128(const u16* A, const u16* __restrict__ Brep,
                  const float* __restrict__ bias, u16* out, int tid) {
    int l = tid & 63, w = tid >> 6;
    int lr = l & 15, lq = l >> 4;
    int Mt = w & 3, Ntb = (w >> 2) * 4;
    f32x4 z = {0.f, 0.f, 0.f, 0.f};
    f32x4 acc[4];
    #pragma unroll
    for (int i = 0; i < 4; ++i) acc[i] = z;
    int arow = Mt * 16 + lr;
    #pragma unroll
    for (int ks = 0; ks < 4; ++ks) {
        short8 af = *(const short8*)(A + swz(arow, ks * 32 + lq * 8));
        #pragma unroll
        for (int i = 0; i < 4; ++i) {
            int nt = Ntb + i;
            short8 bfr = *(const short8*)(Brep + (((nt << 2) + ks) * 64 + l) * 8);
            acc[i] = MFMA(af, bfr, acc[i]);
        }
    }
    #pragma unroll
    for (int i = 0; i < 4; ++i) {
        int col = (Ntb + i) * 16 + lr;
        float bv = bias[col];
        #pragma unroll
        for (int r = 0; r < 4; ++r) {
            int row = Mt * 16 + lq * 4 + r;
            float v = acc[i][r] + bv;
            if (MODE == 2) v = b2f(A[swz(row, col)]) + fmaxf(v, 0.f);
            out[swz(row, col)] = f2b(v);
        }
    }
}

// m0 scores directly from X tiles via precomputed qk table; fused in-wave softmax.
// Wave w owns rows w and w+8 (row = h*4+q); lane = k. A -> SA[row*64+k].
template <int NT>
DEVI void score_m0(const u16* T1, const u16* T2, const float* __restrict__ qk,
                   float* SA, int tid) {
    #pragma unroll
    for (int ii = 0; ii < 2; ++ii) {
        int row = (tid >> 6) + ii * 8;
        int k = tid & 63;
        const float* qr = qk + row * (NT * 128);
        float s = 0.f;
        #pragma unroll
        for (int t = 0; t < NT; ++t) {
            const u16* T = t ? T2 : T1;
            const float* qt = qr + t * 128;
            #pragma unroll
            for (int jg = 0; jg < 16; ++jg) {
                short8 v8 = *(const short8*)(T + swz(k, jg * 8));
                f32x4 qa = *(const f32x4*)(qt + jg * 8);
                f32x4 qb = *(const f32x4*)(qt + jg * 8 + 4);
                s += b2f((u16)v8[0]) * qa[0] + b2f((u16)v8[1]) * qa[1]
                   + b2f((u16)v8[2]) * qa[2] + b2f((u16)v8[3]) * qa[3]
                   + b2f((u16)v8[4]) * qb[0] + b2f((u16)v8[5]) * qb[1]
                   + b2f((u16)v8[6]) * qb[2] + b2f((u16)v8[7]) * qb[3];
            }
        }
        s = (s + qk[16 * NT * 128 + row]) * SCALE;
        float m = s;
        #pragma unroll
        for (int off = 1; off < 64; off <<= 1) m = fmaxf(m, __shfl_xor(m, off));
        float e = __expf(s - m);
        float su = e;
        #pragma unroll
        for (int off = 1; off < 64; off <<= 1) su += __shfl_xor(su, off);
        SA[row * 64 + k] = e / su;
    }
    // no barrier: SA consumed only after vq_pass's internal+final barriers
}

// Combined V/Q projection: reads X tiles (T1,T2), accumulates both GEMMs in regs,
// then overwrites Dv/Dq (which may alias T1/T2).
template <int NT>
DEVI void vq_pass(const u16* T1, const u16* T2,
                  const u16* __restrict__ Bv, const u16* __restrict__ Bq,
                  const float* __restrict__ bv, const float* __restrict__ bq,
                  u16* Dv, u16* Dq, int tid) {
    int l = tid & 63, w = tid >> 6;
    int lr = l & 15, lq = l >> 4;
    int Mt = w & 3, Ntb = (w >> 2) * 4;
    f32x4 z = {0.f, 0.f, 0.f, 0.f};
    f32x4 aV[4], aQ[4];
    #pragma unroll
    for (int i = 0; i < 4; ++i) { aV[i] = z; aQ[i] = z; }
    #pragma unroll
    for (int p = 0; p < NT; ++p) {
        const u16* At = p ? T2 : T1;
        #pragma unroll
        for (int ks = 0; ks < 4; ++ks) {
            short8 af = *(const short8*)(At + swz(Mt * 16 + lr, ks * 32 + lq * 8));
            int kk = p * 4 + ks;
            #pragma unroll
            for (int i = 0; i < 4; ++i) {
                int nt = Ntb + i;
                short8 b1 = *(const short8*)(Bv + ((nt * (4 * NT) + kk) * 64 + l) * 8);
                aV[i] = MFMA(af, b1, aV[i]);
                short8 b2 = *(const short8*)(Bq + ((nt * (4 * NT) + kk) * 64 + l) * 8);
                aQ[i] = MFMA(af, b2, aQ[i]);
            }
        }
    }
    __syncthreads();   // all X reads (score + this pass) complete
    #pragma unroll
    for (int i = 0; i < 4; ++i) {
        int col = (Ntb + i) * 16 + lr;
        float bvv = bv[col], bqv = bq[col];
        #pragma unroll
        for (int r = 0; r < 4; ++r) {
            int row = Mt * 16 + lq * 4 + r;
            Dv[swz(row, col)] = f2b(aV[i][r] + bvv);
            Dq[swz(row, col)] = f2b(aQ[i][r] + bqv);
        }
    }
    __syncthreads();
}

// O^T = qpre + A*V -> SC[n*4+q]
DEVI void ot_phase(const float* __restrict__ qpre, const float* SA, const u16* V,
                   float* SC, int tid) {
    int q = tid & 3, n = tid >> 2, h = n >> 5;
    float o = qpre[q * 128 + n];
    const float* ar = SA + (h * 4 + q) * 64;
    #pragma unroll 8
    for (int k8 = 0; k8 < 16; ++k8) {
        f32x4 a4 = *(const f32x4*)(ar + k8 * 4);
        #pragma unroll
        for (int j = 0; j < 4; ++j) o += a4[j] * b2f(V[swz(k8 * 4 + j, n)]);
    }
    SC[n * 4 + q] = o;
    __syncthreads();
}

// O@wo (k-split 2, partials in SA) then H'^T = O + relu(.+bo) -> SC[512+n*4+q]
DEVI void ffn_m0(const float* __restrict__ woT, const float* __restrict__ bo,
                 float* SA, float* SC, int tid) {
    if (tid < 256) {
        int n = tid & 127, c = tid >> 7;
        const float* wp = woT + n * 128 + c * 64;
        f32x4 acc = {0.f, 0.f, 0.f, 0.f};
        #pragma unroll 4
        for (int k4 = 0; k4 < 16; ++k4) {
            f32x4 w4 = *(const f32x4*)(wp + k4 * 4);
            #pragma unroll
            for (int j = 0; j < 4; ++j) {
                f32x4 o4 = *(const f32x4*)(SC + (c * 64 + k4 * 4 + j) * 4);
                acc[0] += o4[0] * w4[j]; acc[1] += o4[1] * w4[j];
                acc[2] += o4[2] * w4[j]; acc[3] += o4[3] * w4[j];
            }
        }
        *(f32x4*)(SA + c * 512 + n * 4) = acc;
    }
    __syncthreads();
    {
        int q = tid & 3, n = tid >> 2;
        float val = SA[n * 4 + q] + SA[512 + n * 4 + q] + bo[n];
        SC[512 + n * 4 + q] = SC[n * 4 + q] + fmaxf(val, 0.f);
    }
    __syncthreads();
}

// m1 attention, fully thread-local probs: K2/V2 -> SA, then thread (h,q) updates
// its 32-col slice of QpO in place.
DEVI void att_m1(u16* QpO, const float* __restrict__ wkT, const float* __restrict__ bk,
                 const float* __restrict__ wvT, const float* __restrict__ bv,
                 float* SA, const float* HT, int tid) {
    if (tid < 256) {   // K2 -> SA[0..512), V2 -> SA[512..1024)
        int n = tid & 127, half = tid >> 7;
        const float* wp = (half ? wvT : wkT) + n * 128;
        f32x4 acc = {0.f, 0.f, 0.f, 0.f};
        #pragma unroll 4
        for (int j4 = 0; j4 < 32; ++j4) {
            f32x4 w4 = *(const f32x4*)(wp + j4 * 4);
            #pragma unroll
            for (int j = 0; j < 4; ++j) {
                f32x4 h4 = *(const f32x4*)(HT + (j4 * 4 + j) * 4);
                acc[0] += h4[0] * w4[j]; acc[1] += h4[1] * w4[j];
                acc[2] += h4[2] * w4[j]; acc[3] += h4[3] * w4[j];
            }
        }
        float bb = (half ? bv : bk)[n];
        float* dst = SA + half * 512;
        dst[n] = acc[0] + bb; dst[128 + n] = acc[1] + bb;
        dst[256 + n] = acc[2] + bb; dst[384 + n] = acc[3] + bb;
    }
    __syncthreads();
    if (tid < 256) {
        int h = tid >> 6, q = tid & 63;
        const float* kb = SA + h * 32;
        short8 qf[4];
        f32x4 s = {0.f, 0.f, 0.f, 0.f};
        #pragma unroll
        for (int d8 = 0; d8 < 4; ++d8) {
            qf[d8] = *(const short8*)(QpO + swz(q, h * 32 + d8 * 8));
            #pragma unroll
            for (int j = 0; j < 8; ++j) {
                float qv = b2f((u16)qf[d8][j]);
                int dd = d8 * 8 + j;
                s[0] += qv * kb[dd];       s[1] += qv * kb[128 + dd];
                s[2] += qv * kb[256 + dd]; s[3] += qv * kb[384 + dd];
            }
        }
        float s0 = s[0] * SCALE, s1 = s[1] * SCALE, s2 = s[2] * SCALE, s3 = s[3] * SCALE;
        float m = fmaxf(fmaxf(s0, s1), fmaxf(s2, s3));
        s0 = __expf(s0 - m); s1 = __expf(s1 - m); s2 = __expf(s2 - m); s3 = __expf(s3 - m);
        float inv = 1.f / (s0 + s1 + s2 + s3);
        s0 *= inv; s1 *= inv; s2 *= inv; s3 *= inv;
        const float* v2 = SA + 512 + h * 32;
        #pragma unroll
        for (int d8 = 0; d8 < 4; ++d8) {
            short8 o8;
            #pragma unroll
            for (int j = 0; j < 8; ++j) {
                int dd = d8 * 8 + j;
                float o = b2f((u16)qf[d8][j])
                        + s0 * v2[dd] + s1 * v2[128 + dd]
                        + s2 * v2[256 + dd] + s3 * v2[384 + dd];
                o8[j] = (short)f2b(o);
            }
            *(short8*)(QpO + swz(q, h * 32 + d8 * 8)) = o8;
        }
    }
    __syncthreads();
}

__global__ __launch_bounds__(512, 3) void fused_kernel(Params P) {
    __shared__ __align__(16) u16 R1[64 * 128];   // 16 KB
    __shared__ __align__(16) u16 R2[64 * 128];   // 16 KB
    __shared__ __align__(16) float SA[1024];     // 4 KB
    __shared__ __align__(16) float SC[1024];     // 4 KB  -> 40 KB total

    const int b = blockIdx.x;
    const int tid = threadIdx.x;
    const int l = tid & 63, w = tid >> 6;
    const int lr = l & 15, lq = l >> 4;
    const int Mt = w & 3, Ntb = (w >> 2) * 4;

    const float* v_in = P.in[0] + b * (64 * 256);
    const float* W_in = P.in[1] + b * (64 * 64);
    const float* Q_in = P.in[2] + b * 256;
    const float* ft = P.ft;

    f32x4 z = {0.f, 0.f, 0.f, 0.f};

    // ---- Stage Vh = v + W@pe_w + pe_b into R1 (cols 0..127) / R2 (cols 128..255) ----
    {
        const float* wrow = W_in + (Mt * 16 + lr) * 64 + lq * 8;
        #pragma unroll 1
        for (int p = 0; p < 2; ++p) {
            f32x4 ar[4];
            #pragma unroll
            for (int i = 0; i < 4; ++i) ar[i] = z;
            #pragma unroll
            for (int ks = 0; ks < 2; ++ks) {
                f32x4 w0 = *(const f32x4*)(wrow + ks * 32);
                f32x4 w1 = *(const f32x4*)(wrow + ks * 32 + 4);
                short8 af;
                #pragma unroll
                for (int j = 0; j < 4; ++j) { af[j] = (short)f2b(w0[j]); af[4 + j] = (short)f2b(w1[j]); }
                #pragma unroll
                for (int i = 0; i < 4; ++i) {
                    int ntg = p * 8 + Ntb + i;
                    short8 bfr = *(const short8*)(P.wrep + RW_PEW + ((ntg * 2 + ks) * 64 + l) * 8);
                    ar[i] = MFMA(af, bfr, ar[i]);
                }
            }
            u16* dst = p ? R2 : R1;
            #pragma unroll
            for (int i = 0; i < 4; ++i) {
                int coll = (Ntb + i) * 16 + lr;
                int colg = p * 128 + coll;
                float pb = P.in[4][colg];
                #pragma unroll
                for (int r = 0; r < 4; ++r) {
                    int row = Mt * 16 + lq * 4 + r;
                    dst[swz(row, coll)] = f2b(ar[i][r] + pb + v_in[row * 256 + colg]);
                }
            }
        }
        __syncthreads();
    }

    // ---- ISAB1 ----
    score_m0<2>(R1, R2, P.qk1, SA, tid);                                   // A -> SA
    vq_pass<2>(R1, R2, P.wrep + RW_I1M0_WV, P.wrep + RW_I1M1_WQ,
               P.in[11], P.in[15], R1, R2, tid);                           // Vp->R1, Qp1->R2
    ot_phase(P.qpre, SA, R1, SC, tid);                                     // O^T -> SC
    ffn_m0(ft + FT_I1M0_WO, P.in[13], SA, SC, tid);                        // H1'^T -> SC+512
    att_m1(R2, ft + FT_I1M1_WK, P.in[17], ft + FT_I1M1_WV, P.in[19],
           SA, SC + 512, tid);                                             // O2 in place (R2)
    gemm128<2>(R2, P.wrep + RW_I1M1_WO, P.in[21], R1, tid);                // X -> R1
    __syncthreads();
    // ---- ISAB2 ----
    score_m0<1>(R1, R1, P.qk2, SA, tid);
    vq_pass<1>(R1, R1, P.wrep + RW_I2M0_WV, P.wrep + RW_I2M1_WQ,
               P.in[28], P.in[32], R2, R1, tid);                           // Vp3->R2, Qp3->R1
    ot_phase(P.qpre + 512, SA, R2, SC, tid);
    ffn_m0(ft + FT_I2M0_WO, P.in[30], SA, SC, tid);                        // H2'^T -> SC+512
    att_m1(R1, ft + FT_I2M1_WK, P.in[34], ft + FT_I2M1_WV, P.in[36],
           SA, SC + 512, tid);                                             // O4 in place (R1)
    gemm128<2>(R1, P.wrep + RW_I2M1_WO, P.in[38], R2, tid);                // Xf -> R2
    __syncthreads();

    // ---- decoder MAB ----
    gemm128<0>(R2, P.wrep + RW_DEC_WV, P.in[44], R1, tid);                 // Vpd -> R1
    {   // Qd partials: [1,256]@[256,128], k split 4 -> SA
        int n = tid & 127, c = tid >> 7;
        const float* wp = ft + FT_DEC_WQ + n * 256 + c * 64;
        const float* qq = Q_in + c * 64;
        float acc = 0.f;
        #pragma unroll 8
        for (int k4 = 0; k4 < 16; ++k4) {
            f32x4 w4 = *(const f32x4*)(wp + k4 * 4);
            f32x4 q4 = *(const f32x4*)(qq + k4 * 4);
            acc += q4[0] * w4[0] + q4[1] * w4[1] + q4[2] * w4[2] + q4[3] * w4[3];
        }
        SA[c * 128 + n] = acc;
    }
    __syncthreads();
    if (tid < 128) {   // Qd -> SC[0..128)
        SC[tid] = SA[tid] + SA[128 + tid] + SA[256 + tid] + SA[384 + tid] + P.in[40][tid];
    }
    __syncthreads();
    {   // qkd[h,j] = sum_{d in h} Qd[d]*dec_wk[j,d] -> SA[h*128+j]; bias dot -> SA[512+h]
        int h2 = tid >> 7, j = tid & 127;
        const float* qd = SC + h2 * 32;
        const float* wp = P.in[41] + j * 128 + h2 * 32;
        float s = 0.f;
        #pragma unroll
        for (int d8 = 0; d8 < 8; ++d8) {
            f32x4 q4 = *(const f32x4*)(qd + d8 * 4);
            f32x4 w4 = *(const f32x4*)(wp + d8 * 4);
            s += q4[0] * w4[0] + q4[1] * w4[1] + q4[2] * w4[2] + q4[3] * w4[3];
        }
        SA[h2 * 128 + j] = s;
        if (tid < 4) {
            const float* qd2 = SC + tid * 32;
            const float* bp = P.in[42] + tid * 32;
            float sb = 0.f;
            #pragma unroll
            for (int d = 0; d < 32; ++d) sb += qd2[d] * bp[d];
            SA[512 + tid] = sb;
        }
    }
    __syncthreads();
    if (w < 4) {   // scores from Xf (R2) via qkd; fused softmax -> SA[768+h*64+k]
        int h = w, k = l;
        const float* kd = SA + h * 128;
        float s = 0.f;
        #pragma unroll
        for (int jg = 0; jg < 16; ++jg) {
            short8 x8 = *(const short8*)(R2 + swz(k, jg * 8));
            f32x4 qa = *(const f32x4*)(kd + jg * 8);
            f32x4 qb = *(const f32x4*)(kd + jg * 8 + 4);
            s += b2f((u16)x8[0]) * qa[0] + b2f((u16)x8[1]) * qa[1]
               + b2f((u16)x8[2]) * qa[2] + b2f((u16)x8[3]) * qa[3]
               + b2f((u16)x8[4]) * qb[0] + b2f((u16)x8[5]) * qb[1]
               + b2f((u16)x8[6]) * qb[2] + b2f((u16)x8[7]) * qb[3];
        }
        s = (s + SA[512 + h]) * SCALE;
        float m = s;
        #pragma unroll
        for (int off = 1; off < 64; off <<= 1) m = fmaxf(m, __shfl_xor(m, off));
        float e = __expf(s - m);
        float su = e;
        #pragma unroll
        for (int off = 1; off < 64; off <<= 1) su += __shfl_xor(su, off);
        SA[768 + h * 64 + k] = e / su;
    }
    __syncthreads();
    if (tid < 128) {   // O5 = Qd + A*Vpd -> SC[128..256)
        int n = tid, h = n >> 5;
        float o = SC[n];
        const float* arr = SA + 768 + h * 64;
        #pragma unroll 8
        for (int k8 = 0; k8 < 16; ++k8) {
            f32x4 a4 = *(const f32x4*)(arr + k8 * 4);
            #pragma unroll
            for (int j = 0; j < 4; ++j) o += a4[j] * b2f(R1[swz(k8 * 4 + j, n)]);
        }
        SC[128 + n] = o;
    }
    __syncthreads();
    if (tid < 256) {   // O5@dec_wo partials -> SA[0..256)
        int n = tid & 127, c = tid >> 7;
        const float* wp = ft + FT_DEC_WO + n * 128 + c * 64;
        const float* ov = SC + 128 + c * 64;
        float acc = 0.f;
        #pragma unroll 8
        for (int k4 = 0; k4 < 16; ++k4) {
            f32x4 w4 = *(const f32x4*)(wp + k4 * 4);
            f32x4 o4 = *(const f32x4*)(ov + k4 * 4);
            acc += o4[0] * w4[0] + o4[1] * w4[1] + o4[2] * w4[2] + o4[3] * w4[3];
        }
        SA[c * 128 + n] = acc;
    }
    __syncthreads();
    if (tid < 128) {   // o = O5 + relu(... + bo) -> SC[256..384)
        float val = SA[tid] + SA[128 + tid] + P.in[46][tid];
        SC[256 + tid] = SC[128 + tid] + fmaxf(val, 0.f);
    }
    __syncthreads();
    {   // out = o @ out_w + out_b, k split 2 -> SA[c*256+j]
        int j = tid & 255, c = tid >> 8;
        const float* wp = ft + FT_OUT_W + j * 128 + c * 64;
        const float* ov = SC + 256 + c * 64;
        float acc = 0.f;
        #pragma unroll 8
        for (int k4 = 0; k4 < 16; ++k4) {
            f32x4 w4 = *(const f32x4*)(wp + k4 * 4);
            f32x4 o4 = *(const f32x4*)(ov + k4 * 4);
            acc += o4[0] * w4[0] + o4[1] * w4[1] + o4[2] * w4[2] + o4[3] * w4[3];
        }
        SA[c * 256 + j] = acc;
    }
    __syncthreads();
    if (tid < 256) {
        P.out[b * 256 + tid] = SA[tid] + SA[256 + tid] + P.in[48][tid];
    }
}

extern "C" void kernel_launch(void* const* d_in, const int* in_sizes, int n_in,
                              void* d_out, int out_size, void* d_ws, size_t ws_size,
                              hipStream_t stream) {
    RepArgs ra;
    const int srcidx[11] = {3, 8, 10, 14, 20, 25, 27, 31, 37, 41, 43};
    for (int i = 0; i < 11; ++i) ra.src[i] = (const float*)d_in[srcidx[i]];
    const int tidx[9] = {12, 29, 16, 18, 33, 35, 45, 39, 47};
    for (int i = 0; i < 9; ++i) ra.tsrc[i] = (const float*)d_in[tidx[i]];
    ra.dst = (u16*)d_ws;
    ra.fdst = (float*)((char*)d_ws + RW_END * 2);
    ra.qpre = ra.fdst + FQ_QPRE - 0;   // = fdst + FT_END
    ra.qpre = ra.fdst + FT_END;
    ra.I1 = (const float*)d_in[5];  ra.wq1 = (const float*)d_in[6];  ra.bq1 = (const float*)d_in[7];
    ra.I2 = (const float*)d_in[22]; ra.wq2 = (const float*)d_in[23]; ra.bq2 = (const float*)d_in[24];
    repack_kernel<<<204, 256, 0, stream>>>(ra);

    QkArgs qa;
    qa.qpre = ra.qpre;
    qa.wk1 = (const float*)d_in[8];  qa.bk1 = (const float*)d_in[9];
    qa.wk2 = (const float*)d_in[25]; qa.bk2 = (const float*)d_in[26];
    qa.qk1 = ra.fdst + FQ_QK1;
    qa.qk2 = ra.fdst + FQ_QK2;
    qk_kernel<<<25, 256, 0, stream>>>(qa);

    Params P;
    for (int i = 0; i < 49; ++i) P.in[i] = (const float*)d_in[i];
    P.wrep = (const u16*)d_ws;
    P.ft = (const float*)((char*)d_ws + RW_END * 2);
    P.qpre = P.ft + FT_END;
    P.qk1 = P.ft + FQ_QK1;
    P.qk2 = P.ft + FQ_QK2;
    P.out = (float*)d_out;
    fused_kernel<<<4096, 512, 0, stream>>>(P);
}

// Round 9
// 1474.794 us; speedup vs baseline: 1.3433x; 1.2649x over previous
//
#include <hip/hip_runtime.h>
#include <hip/hip_bf16.h>

typedef unsigned short u16;
typedef unsigned int u32;
typedef __attribute__((ext_vector_type(8))) short short8;
typedef __attribute__((ext_vector_type(4))) float f32x4;

#define DEVI static __device__ __forceinline__

DEVI u16 f2b(float f) {
    union { float f; unsigned v; } x; x.f = f;
    unsigned r = x.v + 0x7fffu + ((x.v >> 16) & 1u);
    return (u16)(r >> 16);
}
DEVI float b2f(u16 u) { union { unsigned v; float f; } x; x.v = ((unsigned)u) << 16; return x.f; }

#define MFMA(a, b, c) __builtin_amdgcn_mfma_f32_16x16x32_bf16((a), (b), (c), 0, 0, 0)

// XOR-swizzle for [64][128] bf16 A-tiles (16B granule permuted by row&7).
DEVI int swz(int row, int col) {
    return row * 128 + ((((col >> 3) ^ (row & 7))) << 3) + (col & 7);
}

// ws layout: bf16 MFMA B-fragments, then f32 transposed weights, qpre, qk tables.
#define RW_PEW     0
#define RW_I1M0_WK 16384
#define RW_I1M0_WV 49152
#define RW_I1M1_WQ 81920
#define RW_I1M1_WO 114688
#define RW_I2M0_WK 131072
#define RW_I2M0_WV 147456
#define RW_I2M1_WQ 163840
#define RW_I2M1_WO 180224
#define RW_DEC_WK  196608
#define RW_DEC_WV  212992
#define RW_END     229376   // bf16 elems

#define FT_I1M0_WO 0
#define FT_I2M0_WO 16384
#define FT_I1M1_WK 32768
#define FT_I1M1_WV 49152
#define FT_I2M1_WK 65536
#define FT_I2M1_WV 81920
#define FT_DEC_WO  98304
#define FT_DEC_WQ  114688
#define FT_OUT_W   147456
#define FT_END     180224
// f32 appendix (offsets in floats from ft base)
#define FQ_QPRE    FT_END              // [2][4][128]
#define FQ_QK1     (FT_END + 1024)     // [16][256] + [16] bias-dots
#define FQ_QK2     (FT_END + 1024 + 4112)  // [16][128] + [16]

#define SCALE 0.08838834764831845f  // 1/sqrt(128)

struct Params {
    const float* in[49];
    const u16* wrep;
    const float* ft;
    const float* qpre;   // [2][4][128]
    const float* qk1;    // [16][256]+[16]
    const float* qk2;    // [16][128]+[16]
    float* out;
};

struct RepArgs {
    const float* src[11];
    const float* tsrc[9];
    u16* dst;
    float* fdst;
    float* qpre;
    const float* I1; const float* wq1; const float* bq1;
    const float* I2; const float* wq2; const float* bq2;
};

__global__ void repack_kernel(RepArgs a) {
    const int offs[11] = {RW_PEW, RW_I1M0_WK, RW_I1M0_WV, RW_I1M1_WQ, RW_I1M1_WO,
                          RW_I2M0_WK, RW_I2M0_WV, RW_I2M1_WQ, RW_I2M1_WO, RW_DEC_WK, RW_DEC_WV};
    const int Ks[11] = {64, 256, 256, 256, 128, 128, 128, 128, 128, 128, 128};
    const int Ns[11] = {256, 128, 128, 128, 128, 128, 128, 128, 128, 128, 128};
    int t = blockIdx.x * 256 + threadIdx.x;
    if (t < 28672) {
        int m = 0, u = t;
        for (m = 0; m < 11; ++m) {
            int un = (Ks[m] * Ns[m]) >> 3;
            if (u < un) break;
            u -= un;
        }
        int l = u & 63, f = u >> 6;
        int ksteps = Ks[m] >> 5;
        int nt = f / ksteps, ks = f - nt * ksteps;
        int N = Ns[m];
        const float* s = a.src[m] + (ks * 32 + (l >> 4) * 8) * N + nt * 16 + (l & 15);
        u16* d = a.dst + offs[m] + ((f * 64 + l) << 3);
        short8 v;
        #pragma unroll
        for (int j = 0; j < 8; ++j) v[j] = (short)f2b(s[j * N]);
        *(short8*)d = v;
    } else if (t < 51200) {
        const int TK[9] = {128, 128, 128, 128, 128, 128, 128, 256, 128};
        const int TN[9] = {128, 128, 128, 128, 128, 128, 128, 128, 256};
        const int TOFF[9] = {FT_I1M0_WO, FT_I2M0_WO, FT_I1M1_WK, FT_I1M1_WV,
                             FT_I2M1_WK, FT_I2M1_WV, FT_DEC_WO, FT_DEC_WQ, FT_OUT_W};
        int u = t - 28672;
        int m = 0;
        for (m = 0; m < 9; ++m) {
            int un = (TK[m] * TN[m]) >> 3;
            if (u < un) break;
            u -= un;
        }
        int K = TK[m], N = TN[m];
        int kc = K >> 3;
        int n = u / kc, k0 = (u - n * kc) << 3;
        const float* s = a.tsrc[m] + k0 * N + n;
        float* d = a.fdst + TOFF[m] + n * K + k0;
        f32x4 v0, v1;
        #pragma unroll
        for (int j = 0; j < 4; ++j) v0[j] = s[j * N];
        #pragma unroll
        for (int j = 0; j < 4; ++j) v1[j] = s[(4 + j) * N];
        *(f32x4*)d = v0;
        *(f32x4*)(d + 4) = v1;
    } else {
        int q_t = t - 51200;             // 0..1023
        int which = q_t >> 9, q = (q_t >> 7) & 3, n = q_t & 127;
        const float* I  = which ? a.I2  : a.I1;
        const float* wq = which ? a.wq2 : a.wq1;
        const float* bq = which ? a.bq2 : a.bq1;
        float acc = bq[n];
        for (int k = 0; k < 128; ++k) acc += I[q * 128 + k] * wq[k * 128 + n];
        a.qpre[q_t] = acc;
    }
}

struct QkArgs {
    const float* qpre;
    const float* wk1; const float* bk1;   // [256][128], [128]
    const float* wk2; const float* bk2;   // [128][128], [128]
    float* qk1; float* qk2;
};

// qkh[h,q,j] = sum_{d in head h} qpre[q,d] * wk[j,d]; bias-dots appended.
__global__ void qk_kernel(QkArgs a) {
    int t = blockIdx.x * 256 + threadIdx.x;
    if (t < 4096) {
        int r = t >> 8, j = t & 255;
        int h = r >> 2, q = r & 3;
        const float* qp = a.qpre + q * 128 + h * 32;
        const float* wp = a.wk1 + j * 128 + h * 32;
        float s = 0.f;
        #pragma unroll
        for (int d = 0; d < 32; ++d) s += qp[d] * wp[d];
        a.qk1[r * 256 + j] = s;
    } else if (t < 6144) {
        int u = t - 4096;
        int r = u >> 7, j = u & 127;
        int h = r >> 2, q = r & 3;
        const float* qp = a.qpre + 512 + q * 128 + h * 32;
        const float* wp = a.wk2 + j * 128 + h * 32;
        float s = 0.f;
        #pragma unroll
        for (int d = 0; d < 32; ++d) s += qp[d] * wp[d];
        a.qk2[r * 128 + j] = s;
    } else if (t < 6160) {
        int r = t - 6144; int h = r >> 2, q = r & 3;
        const float* qp = a.qpre + q * 128 + h * 32;
        const float* bp = a.bk1 + h * 32;
        float s = 0.f;
        #pragma unroll
        for (int d = 0; d < 32; ++d) s += qp[d] * bp[d];
        a.qk1[4096 + r] = s;
    } else if (t < 6176) {
        int r = t - 6160; int h = r >> 2, q = r & 3;
        const float* qp = a.qpre + 512 + q * 128 + h * 32;
        const float* bp = a.bk2 + h * 32;
        float s = 0.f;
        #pragma unroll
        for (int d = 0; d < 32; ++d) s += qp[d] * bp[d];
        a.qk2[2048 + r] = s;
    }
}

// [64,128] = A(swizzled) @ Brep(K=128) + bias.  MODE 0: plain out; MODE 2: A + relu(D+bias).
template <int MODE>
DEVI void gemm128(const u16* A, const u16* __restrict__ Brep,
                  const float* __restrict__ bias, u16* out, int tid) {
    int l = tid & 63, w = tid >> 6;
    int lr = l & 15, lq = l >> 4;
    int Mt = w & 3, Ntb = (w >> 2) * 4;
    f32x4 z = {0.f, 0.f, 0.f, 0.f};
    f32x4 acc[4];
    #pragma unroll
    for (int i = 0; i < 4; ++i) acc[i] = z;
    int arow = Mt * 16 + lr;
    #pragma unroll
    for (int ks = 0; ks < 4; ++ks) {
        short8 af = *(const short8*)(A + swz(arow, ks * 32 + lq * 8));
        #pragma unroll
        for (int i = 0; i < 4; ++i) {
            int nt = Ntb + i;
            short8 bfr = *(const short8*)(Brep + (((nt << 2) + ks) * 64 + l) * 8);
            acc[i] = MFMA(af, bfr, acc[i]);
        }
    }
    #pragma unroll
    for (int i = 0; i < 4; ++i) {
        int col = (Ntb + i) * 16 + lr;
        float bv = bias[col];
        #pragma unroll
        for (int r = 0; r < 4; ++r) {
            int row = Mt * 16 + lq * 4 + r;
            float v = acc[i][r] + bv;
            if (MODE == 2) v = b2f(A[swz(row, col)]) + fmaxf(v, 0.f);
            out[swz(row, col)] = f2b(v);
        }
    }
}

// m0 scores directly from X tiles via precomputed qk table; fused in-wave softmax.
// Wave w owns rows w and w+8 (row = h*4+q); lane = k. A -> SA[row*64+k].
template <int NT>
DEVI void score_m0(const u16* T1, const u16* T2, const float* __restrict__ qk,
                   float* SA, int tid) {
    #pragma unroll
    for (int ii = 0; ii < 2; ++ii) {
        int row = (tid >> 6) + ii * 8;
        int k = tid & 63;
        const float* qr = qk + row * (NT * 128);
        float s = 0.f;
        #pragma unroll
        for (int t = 0; t < NT; ++t) {
            const u16* T = t ? T2 : T1;
            const float* qt = qr + t * 128;
            #pragma unroll
            for (int jg = 0; jg < 16; ++jg) {
                short8 v8 = *(const short8*)(T + swz(k, jg * 8));
                f32x4 qa = *(const f32x4*)(qt + jg * 8);
                f32x4 qb = *(const f32x4*)(qt + jg * 8 + 4);
                s += b2f((u16)v8[0]) * qa[0] + b2f((u16)v8[1]) * qa[1]
                   + b2f((u16)v8[2]) * qa[2] + b2f((u16)v8[3]) * qa[3]
                   + b2f((u16)v8[4]) * qb[0] + b2f((u16)v8[5]) * qb[1]
                   + b2f((u16)v8[6]) * qb[2] + b2f((u16)v8[7]) * qb[3];
            }
        }
        s = (s + qk[16 * NT * 128 + row]) * SCALE;
        float m = s;
        #pragma unroll
        for (int off = 1; off < 64; off <<= 1) m = fmaxf(m, __shfl_xor(m, off));
        float e = __expf(s - m);
        float su = e;
        #pragma unroll
        for (int off = 1; off < 64; off <<= 1) su += __shfl_xor(su, off);
        SA[row * 64 + k] = e / su;
    }
    // no barrier: SA consumed only after vq_pass's internal+final barriers
}

// Combined V/Q projection: reads X tiles (T1,T2), accumulates both GEMMs in regs,
// then overwrites Dv/Dq (which may alias T1/T2).
template <int NT>
DEVI void vq_pass(const u16* T1, const u16* T2,
                  const u16* __restrict__ Bv, const u16* __restrict__ Bq,
                  const float* __restrict__ bv, const float* __restrict__ bq,
                  u16* Dv, u16* Dq, int tid) {
    int l = tid & 63, w = tid >> 6;
    int lr = l & 15, lq = l >> 4;
    int Mt = w & 3, Ntb = (w >> 2) * 4;
    f32x4 z = {0.f, 0.f, 0.f, 0.f};
    f32x4 aV[4], aQ[4];
    #pragma unroll
    for (int i = 0; i < 4; ++i) { aV[i] = z; aQ[i] = z; }
    #pragma unroll
    for (int p = 0; p < NT; ++p) {
        const u16* At = p ? T2 : T1;
        #pragma unroll
        for (int ks = 0; ks < 4; ++ks) {
            short8 af = *(const short8*)(At + swz(Mt * 16 + lr, ks * 32 + lq * 8));
            int kk = p * 4 + ks;
            #pragma unroll
            for (int i = 0; i < 4; ++i) {
                int nt = Ntb + i;
                short8 b1 = *(const short8*)(Bv + ((nt * (4 * NT) + kk) * 64 + l) * 8);
                aV[i] = MFMA(af, b1, aV[i]);
                short8 b2 = *(const short8*)(Bq + ((nt * (4 * NT) + kk) * 64 + l) * 8);
                aQ[i] = MFMA(af, b2, aQ[i]);
            }
        }
    }
    __syncthreads();   // all X reads (score + this pass) complete
    #pragma unroll
    for (int i = 0; i < 4; ++i) {
        int col = (Ntb + i) * 16 + lr;
        float bvv = bv[col], bqv = bq[col];
        #pragma unroll
        for (int r = 0; r < 4; ++r) {
            int row = Mt * 16 + lq * 4 + r;
            Dv[swz(row, col)] = f2b(aV[i][r] + bvv);
            Dq[swz(row, col)] = f2b(aQ[i][r] + bqv);
        }
    }
    __syncthreads();
}

// O^T = qpre + A*V -> SC[n*4+q]
DEVI void ot_phase(const float* __restrict__ qpre, const float* SA, const u16* V,
                   float* SC, int tid) {
    int q = tid & 3, n = tid >> 2, h = n >> 5;
    float o = qpre[q * 128 + n];
    const float* ar = SA + (h * 4 + q) * 64;
    #pragma unroll 8
    for (int k8 = 0; k8 < 16; ++k8) {
        f32x4 a4 = *(const f32x4*)(ar + k8 * 4);
        #pragma unroll
        for (int j = 0; j < 4; ++j) o += a4[j] * b2f(V[swz(k8 * 4 + j, n)]);
    }
    SC[n * 4 + q] = o;
    __syncthreads();
}

// O@wo (k-split 2, partials in SA) then H'^T = O + relu(.+bo) -> SC[512+n*4+q]
DEVI void ffn_m0(const float* __restrict__ woT, const float* __restrict__ bo,
                 float* SA, float* SC, int tid) {
    if (tid < 256) {
        int n = tid & 127, c = tid >> 7;
        const float* wp = woT + n * 128 + c * 64;
        f32x4 acc = {0.f, 0.f, 0.f, 0.f};
        #pragma unroll 4
        for (int k4 = 0; k4 < 16; ++k4) {
            f32x4 w4 = *(const f32x4*)(wp + k4 * 4);
            #pragma unroll
            for (int j = 0; j < 4; ++j) {
                f32x4 o4 = *(const f32x4*)(SC + (c * 64 + k4 * 4 + j) * 4);
                acc[0] += o4[0] * w4[j]; acc[1] += o4[1] * w4[j];
                acc[2] += o4[2] * w4[j]; acc[3] += o4[3] * w4[j];
            }
        }
        *(f32x4*)(SA + c * 512 + n * 4) = acc;
    }
    __syncthreads();
    {
        int q = tid & 3, n = tid >> 2;
        float val = SA[n * 4 + q] + SA[512 + n * 4 + q] + bo[n];
        SC[512 + n * 4 + q] = SC[n * 4 + q] + fmaxf(val, 0.f);
    }
    __syncthreads();
}

// m1 attention, fully thread-local probs: K2/V2 -> SA, then thread (h,q) updates
// its 32-col slice of QpO in place.
DEVI void att_m1(u16* QpO, const float* __restrict__ wkT, const float* __restrict__ bk,
                 const float* __restrict__ wvT, const float* __restrict__ bv,
                 float* SA, const float* HT, int tid) {
    if (tid < 256) {   // K2 -> SA[0..512), V2 -> SA[512..1024)
        int n = tid & 127, half = tid >> 7;
        const float* wp = (half ? wvT : wkT) + n * 128;
        f32x4 acc = {0.f, 0.f, 0.f, 0.f};
        #pragma unroll 4
        for (int j4 = 0; j4 < 32; ++j4) {
            f32x4 w4 = *(const f32x4*)(wp + j4 * 4);
            #pragma unroll
            for (int j = 0; j < 4; ++j) {
                f32x4 h4 = *(const f32x4*)(HT + (j4 * 4 + j) * 4);
                acc[0] += h4[0] * w4[j]; acc[1] += h4[1] * w4[j];
                acc[2] += h4[2] * w4[j]; acc[3] += h4[3] * w4[j];
            }
        }
        float bb = (half ? bv : bk)[n];
        float* dst = SA + half * 512;
        dst[n] = acc[0] + bb; dst[128 + n] = acc[1] + bb;
        dst[256 + n] = acc[2] + bb; dst[384 + n] = acc[3] + bb;
    }
    __syncthreads();
    if (tid < 256) {
        int h = tid >> 6, q = tid & 63;
        const float* kb = SA + h * 32;
        short8 qf[4];
        f32x4 s = {0.f, 0.f, 0.f, 0.f};
        #pragma unroll
        for (int d8 = 0; d8 < 4; ++d8) {
            qf[d8] = *(const short8*)(QpO + swz(q, h * 32 + d8 * 8));
            #pragma unroll
            for (int j = 0; j < 8; ++j) {
                float qv = b2f((u16)qf[d8][j]);
                int dd = d8 * 8 + j;
                s[0] += qv * kb[dd];       s[1] += qv * kb[128 + dd];
                s[2] += qv * kb[256 + dd]; s[3] += qv * kb[384 + dd];
            }
        }
        float s0 = s[0] * SCALE, s1 = s[1] * SCALE, s2 = s[2] * SCALE, s3 = s[3] * SCALE;
        float m = fmaxf(fmaxf(s0, s1), fmaxf(s2, s3));
        s0 = __expf(s0 - m); s1 = __expf(s1 - m); s2 = __expf(s2 - m); s3 = __expf(s3 - m);
        float inv = 1.f / (s0 + s1 + s2 + s3);
        s0 *= inv; s1 *= inv; s2 *= inv; s3 *= inv;
        const float* v2 = SA + 512 + h * 32;
        #pragma unroll
        for (int d8 = 0; d8 < 4; ++d8) {
            short8 o8;
            #pragma unroll
            for (int j = 0; j < 8; ++j) {
                int dd = d8 * 8 + j;
                float o = b2f((u16)qf[d8][j])
                        + s0 * v2[dd] + s1 * v2[128 + dd]
                        + s2 * v2[256 + dd] + s3 * v2[384 + dd];
                o8[j] = (short)f2b(o);
            }
            *(short8*)(QpO + swz(q, h * 32 + d8 * 8)) = o8;
        }
    }
    __syncthreads();
}

__global__ __launch_bounds__(512, 2) void fused_kernel(Params P) {
    __shared__ __align__(16) u16 R1[64 * 128];   // 16 KB
    __shared__ __align__(16) u16 R2[64 * 128];   // 16 KB
    __shared__ __align__(16) float SA[1024];     // 4 KB
    __shared__ __align__(16) float SC[1024];     // 4 KB  -> 40 KB total

    const int b = blockIdx.x;
    const int tid = threadIdx.x;
    const int l = tid & 63, w = tid >> 6;
    const int lr = l & 15, lq = l >> 4;
    const int Mt = w & 3, Ntb = (w >> 2) * 4;

    const float* v_in = P.in[0] + b * (64 * 256);
    const float* W_in = P.in[1] + b * (64 * 64);
    const float* Q_in = P.in[2] + b * 256;
    const float* ft = P.ft;

    f32x4 z = {0.f, 0.f, 0.f, 0.f};

    // ---- Stage Vh = v + W@pe_w + pe_b into R1 (cols 0..127) / R2 (cols 128..255) ----
    {
        const float* wrow = W_in + (Mt * 16 + lr) * 64 + lq * 8;
        #pragma unroll 1
        for (int p = 0; p < 2; ++p) {
            f32x4 ar[4];
            #pragma unroll
            for (int i = 0; i < 4; ++i) ar[i] = z;
            #pragma unroll
            for (int ks = 0; ks < 2; ++ks) {
                f32x4 w0 = *(const f32x4*)(wrow + ks * 32);
                f32x4 w1 = *(const f32x4*)(wrow + ks * 32 + 4);
                short8 af;
                #pragma unroll
                for (int j = 0; j < 4; ++j) { af[j] = (short)f2b(w0[j]); af[4 + j] = (short)f2b(w1[j]); }
                #pragma unroll
                for (int i = 0; i < 4; ++i) {
                    int ntg = p * 8 + Ntb + i;
                    short8 bfr = *(const short8*)(P.wrep + RW_PEW + ((ntg * 2 + ks) * 64 + l) * 8);
                    ar[i] = MFMA(af, bfr, ar[i]);
                }
            }
            u16* dst = p ? R2 : R1;
            #pragma unroll
            for (int i = 0; i < 4; ++i) {
                int coll = (Ntb + i) * 16 + lr;
                int colg = p * 128 + coll;
                float pb = P.in[4][colg];
                #pragma unroll
                for (int r = 0; r < 4; ++r) {
                    int row = Mt * 16 + lq * 4 + r;
                    dst[swz(row, coll)] = f2b(ar[i][r] + pb + v_in[row * 256 + colg]);
                }
            }
        }
        __syncthreads();
    }

    // ---- ISAB1 ----
    score_m0<2>(R1, R2, P.qk1, SA, tid);                                   // A -> SA
    vq_pass<2>(R1, R2, P.wrep + RW_I1M0_WV, P.wrep + RW_I1M1_WQ,
               P.in[11], P.in[15], R1, R2, tid);                           // Vp->R1, Qp1->R2
    ot_phase(P.qpre, SA, R1, SC, tid);                                     // O^T -> SC
    ffn_m0(ft + FT_I1M0_WO, P.in[13], SA, SC, tid);                        // H1'^T -> SC+512
    att_m1(R2, ft + FT_I1M1_WK, P.in[17], ft + FT_I1M1_WV, P.in[19],
           SA, SC + 512, tid);                                             // O2 in place (R2)
    gemm128<2>(R2, P.wrep + RW_I1M1_WO, P.in[21], R1, tid);                // X -> R1
    __syncthreads();
    // ---- ISAB2 ----
    score_m0<1>(R1, R1, P.qk2, SA, tid);
    vq_pass<1>(R1, R1, P.wrep + RW_I2M0_WV, P.wrep + RW_I2M1_WQ,
               P.in[28], P.in[32], R2, R1, tid);                           // Vp3->R2, Qp3->R1
    ot_phase(P.qpre + 512, SA, R2, SC, tid);
    ffn_m0(ft + FT_I2M0_WO, P.in[30], SA, SC, tid);                        // H2'^T -> SC+512
    att_m1(R1, ft + FT_I2M1_WK, P.in[34], ft + FT_I2M1_WV, P.in[36],
           SA, SC + 512, tid);                                             // O4 in place (R1)
    gemm128<2>(R1, P.wrep + RW_I2M1_WO, P.in[38], R2, tid);                // Xf -> R2
    __syncthreads();

    // ---- decoder MAB ----
    gemm128<0>(R2, P.wrep + RW_DEC_WV, P.in[44], R1, tid);                 // Vpd -> R1
    {   // Qd partials: [1,256]@[256,128], k split 4 -> SA
        int n = tid & 127, c = tid >> 7;
        const float* wp = ft + FT_DEC_WQ + n * 256 + c * 64;
        const float* qq = Q_in + c * 64;
        float acc = 0.f;
        #pragma unroll 8
        for (int k4 = 0; k4 < 16; ++k4) {
            f32x4 w4 = *(const f32x4*)(wp + k4 * 4);
            f32x4 q4 = *(const f32x4*)(qq + k4 * 4);
            acc += q4[0] * w4[0] + q4[1] * w4[1] + q4[2] * w4[2] + q4[3] * w4[3];
        }
        SA[c * 128 + n] = acc;
    }
    __syncthreads();
    if (tid < 128) {   // Qd -> SC[0..128)
        SC[tid] = SA[tid] + SA[128 + tid] + SA[256 + tid] + SA[384 + tid] + P.in[40][tid];
    }
    __syncthreads();
    {   // qkd[h,j] = sum_{d in h} Qd[d]*dec_wk[j,d] -> SA[h*128+j]; bias dot -> SA[512+h]
        int h2 = tid >> 7, j = tid & 127;
        const float* qd = SC + h2 * 32;
        const float* wp = P.in[41] + j * 128 + h2 * 32;
        float s = 0.f;
        #pragma unroll
        for (int d8 = 0; d8 < 8; ++d8) {
            f32x4 q4 = *(const f32x4*)(qd + d8 * 4);
            f32x4 w4 = *(const f32x4*)(wp + d8 * 4);
            s += q4[0] * w4[0] + q4[1] * w4[1] + q4[2] * w4[2] + q4[3] * w4[3];
        }
        SA[h2 * 128 + j] = s;
        if (tid < 4) {
            const float* qd2 = SC + tid * 32;
            const float* bp = P.in[42] + tid * 32;
            float sb = 0.f;
            #pragma unroll
            for (int d = 0; d < 32; ++d) sb += qd2[d] * bp[d];
            SA[512 + tid] = sb;
        }
    }
    __syncthreads();
    if (w < 4) {   // scores from Xf (R2) via qkd; fused softmax -> SA[768+h*64+k]
        int h = w, k = l;
        const float* kd = SA + h * 128;
        float s = 0.f;
        #pragma unroll
        for (int jg = 0; jg < 16; ++jg) {
            short8 x8 = *(const short8*)(R2 + swz(k, jg * 8));
            f32x4 qa = *(const f32x4*)(kd + jg * 8);
            f32x4 qb = *(const f32x4*)(kd + jg * 8 + 4);
            s += b2f((u16)x8[0]) * qa[0] + b2f((u16)x8[1]) * qa[1]
               + b2f((u16)x8[2]) * qa[2] + b2f((u16)x8[3]) * qa[3]
               + b2f((u16)x8[4]) * qb[0] + b2f((u16)x8[5]) * qb[1]
               + b2f((u16)x8[6]) * qb[2] + b2f((u16)x8[7]) * qb[3];
        }
        s = (s + SA[512 + h]) * SCALE;
        float m = s;
        #pragma unroll
        for (int off = 1; off < 64; off <<= 1) m = fmaxf(m, __shfl_xor(m, off));
        float e = __expf(s - m);
        float su = e;
        #pragma unroll
        for (int off = 1; off < 64; off <<= 1) su += __shfl_xor(su, off);
        SA[768 + h * 64 + k] = e / su;
    }
    __syncthreads();
    if (tid < 128) {   // O5 = Qd + A*Vpd -> SC[128..256)
        int n = tid, h = n >> 5;
        float o = SC[n];
        const float* arr = SA + 768 + h * 64;
        #pragma unroll 8
        for (int k8 = 0; k8 < 16; ++k8) {
            f32x4 a4 = *(const f32x4*)(arr + k8 * 4);
            #pragma unroll
            for (int j = 0; j < 4; ++j) o += a4[j] * b2f(R1[swz(k8 * 4 + j, n)]);
        }
        SC[128 + n] = o;
    }
    __syncthreads();
    if (tid < 256) {   // O5@dec_wo partials -> SA[0..256)
        int n = tid & 127, c = tid >> 7;
        const float* wp = ft + FT_DEC_WO + n * 128 + c * 64;
        const float* ov = SC + 128 + c * 64;
        float acc = 0.f;
        #pragma unroll 8
        for (int k4 = 0; k4 < 16; ++k4) {
            f32x4 w4 = *(const f32x4*)(wp + k4 * 4);
            f32x4 o4 = *(const f32x4*)(ov + k4 * 4);
            acc += o4[0] * w4[0] + o4[1] * w4[1] + o4[2] * w4[2] + o4[3] * w4[3];
        }
        SA[c * 128 + n] = acc;
    }
    __syncthreads();
    if (tid < 128) {   // o = O5 + relu(... + bo) -> SC[256..384)
        float val = SA[tid] + SA[128 + tid] + P.in[46][tid];
        SC[256 + tid] = SC[128 + tid] + fmaxf(val, 0.f);
    }
    __syncthreads();
    {   // out = o @ out_w + out_b, k split 2 -> SA[c*256+j]
        int j = tid & 255, c = tid >> 8;
        const float* wp = ft + FT_OUT_W + j * 128 + c * 64;
        const float* ov = SC + 256 + c * 64;
        float acc = 0.f;
        #pragma unroll 8
        for (int k4 = 0; k4 < 16; ++k4) {
            f32x4 w4 = *(const f32x4*)(wp + k4 * 4);
            f32x4 o4 = *(const f32x4*)(ov + k4 * 4);
            acc += o4[0] * w4[0] + o4[1] * w4[1] + o4[2] * w4[2] + o4[3] * w4[3];
        }
        SA[c * 256 + j] = acc;
    }
    __syncthreads();
    if (tid < 256) {
        P.out[b * 256 + tid] = SA[tid] + SA[256 + tid] + P.in[48][tid];
    }
}

extern "C" void kernel_launch(void* const* d_in, const int* in_sizes, int n_in,
                              void* d_out, int out_size, void* d_ws, size_t ws_size,
                              hipStream_t stream) {
    RepArgs ra;
    const int srcidx[11] = {3, 8, 10, 14, 20, 25, 27, 31, 37, 41, 43};
    for (int i = 0; i < 11; ++i) ra.src[i] = (const float*)d_in[srcidx[i]];
    const int tidx[9] = {12, 29, 16, 18, 33, 35, 45, 39, 47};
    for (int i = 0; i < 9; ++i) ra.tsrc[i] = (const float*)d_in[tidx[i]];
    ra.dst = (u16*)d_ws;
    ra.fdst = (float*)((char*)d_ws + RW_END * 2);
    ra.qpre = ra.fdst + FT_END;
    ra.I1 = (const float*)d_in[5];  ra.wq1 = (const float*)d_in[6];  ra.bq1 = (const float*)d_in[7];
    ra.I2 = (const float*)d_in[22]; ra.wq2 = (const float*)d_in[23]; ra.bq2 = (const float*)d_in[24];
    repack_kernel<<<204, 256, 0, stream>>>(ra);

    QkArgs qa;
    qa.qpre = ra.qpre;
    qa.wk1 = (const float*)d_in[8];  qa.bk1 = (const float*)d_in[9];
    qa.wk2 = (const float*)d_in[25]; qa.bk2 = (const float*)d_in[26];
    qa.qk1 = ra.fdst + FQ_QK1;
    qa.qk2 = ra.fdst + FQ_QK2;
    qk_kernel<<<25, 256, 0, stream>>>(qa);

    Params P;
    for (int i = 0; i < 49; ++i) P.in[i] = (const float*)d_in[i];
    P.wrep = (const u16*)d_ws;
    P.ft = (const float*)((char*)d_ws + RW_END * 2);
    P.qpre = P.ft + FT_END;
    P.qk1 = P.ft + FQ_QK1;
    P.qk2 = P.ft + FQ_QK2;
    P.out = (float*)d_out;
    fused_kernel<<<4096, 512, 0, stream>>>(P);
}